// Round 5
// baseline (164.501 us; speedup 1.0000x reference)
//
#include <hip/hip_runtime.h>
#include <hip/hip_bf16.h>

#define C 128
#define HW 4096
#define NPOS 65536
#define K 1024
#define MB 64             // positions per block
#define NBLK (NPOS/MB)    // 1024
#define RS 136            // zt row stride in ushorts (272 B)
#define IMG_RS 256        // bf16 image row stride bytes

#define ZQ_OFF 0
#define LOSS_OFF 8388608
#define IDX_OFF 8388609
#define COMMIT_OFF 8454145
#define CODE_OFF 8454146

#define WS_EN_OFF 256     // enorm1[1024] fp32
#define WS_IMG_OFF 8192   // bf16 codebook image, 1024*256 B

typedef __bf16 bf16x8 __attribute__((ext_vector_type(8)));
typedef float f32x4 __attribute__((ext_vector_type(4)));

__global__ void vq_prep(const float* __restrict__ emb, unsigned char* __restrict__ img,
                        float* __restrict__ enorm1) {
    int t = threadIdx.x;
    int r = t >> 5, l = t & 31;
    int k = blockIdx.x * 8 + r;
    float4 v = ((const float4*)emb)[k * 32 + l];
    __hip_bfloat16 h0 = __float2bfloat16(v.x), h1 = __float2bfloat16(v.y),
                   h2 = __float2bfloat16(v.z), h3 = __float2bfloat16(v.w);
    ushort4 pk;
    pk.x = *(unsigned short*)&h0; pk.y = *(unsigned short*)&h1;
    pk.z = *(unsigned short*)&h2; pk.w = *(unsigned short*)&h3;
    *(ushort4*)(img + (size_t)k * IMG_RS + l * 8) = pk;
    float s = v.x * v.x + v.y * v.y + v.z * v.z + v.w * v.w;
    #pragma unroll
    for (int off = 16; off; off >>= 1) s += __shfl_xor(s, off);
    if (l == 0) enorm1[k] = s + 1.0f;
}

__global__ __launch_bounds__(256, 3)
void vq_main(const float* __restrict__ z,
             const unsigned char* __restrict__ img, const float* __restrict__ enorm1,
             float* __restrict__ out, float* __restrict__ S, unsigned int* __restrict__ cnt) {
    __shared__ unsigned short zt[MB * RS];   // 17408 B
    __shared__ unsigned int wbest[4][MB];    // 1024 B
    __shared__ unsigned short idxs[MB];
    __shared__ float lred[4];

    const int t = threadIdx.x;
    const int w = t >> 6;
    const int lane = t & 63;
    const int nn = lane & 15;
    const int q = lane >> 4;

    const int n0g = blockIdx.x * MB;
    const int b = n0g >> 12;
    const int hw0 = n0g & (HW - 1);
    const float* zg = z + (size_t)b * C * HW + hw0;

    // stage z tile -> LDS bf16 [pos][c]; thread: pos = t&63, c-quarter = t>>6
    {
        int pos = t & 63;
        int c0b = (t >> 6) * 32;
        #pragma unroll
        for (int i = 0; i < 8; ++i) {
            int c0 = c0b + i * 4;
            float f0 = zg[(size_t)(c0 + 0) * HW + pos];
            float f1 = zg[(size_t)(c0 + 1) * HW + pos];
            float f2 = zg[(size_t)(c0 + 2) * HW + pos];
            float f3 = zg[(size_t)(c0 + 3) * HW + pos];
            __hip_bfloat16 h0 = __float2bfloat16(f0), h1 = __float2bfloat16(f1),
                           h2 = __float2bfloat16(f2), h3 = __float2bfloat16(f3);
            ushort4 pk;
            pk.x = *(unsigned short*)&h0; pk.y = *(unsigned short*)&h1;
            pk.z = *(unsigned short*)&h2; pk.w = *(unsigned short*)&h3;
            *(ushort4*)&zt[pos * RS + c0] = pk;
        }
    }
    __syncthreads();

    // A-frags: 4 M-tiles x 4 K-steps in regs (64 VGPRs), reused for all codes
    bf16x8 a[4][4];
    #pragma unroll
    for (int mt = 0; mt < 4; ++mt)
        #pragma unroll
        for (int ks = 0; ks < 4; ++ks)
            a[mt][ks] = *(bf16x8*)&zt[(mt * 16 + nn) * RS + ks * 32 + q * 8];

    unsigned int best[4][4];
    #pragma unroll
    for (int mt = 0; mt < 4; ++mt)
        #pragma unroll
        for (int r = 0; r < 4; ++r) best[mt][r] = 0xFFFFFFFFu;

    // K-split: wave w owns codes [w*256, w*256+256) = 16 N-tiles of 16 codes
    const int base_w = w * 256;
    const unsigned char* gB = img + (size_t)(base_w + nn) * IMG_RS + q * 16;
    const float* gE = enorm1 + base_w + nn;

    bf16x8 bcur[4], bnxt[4];
    #pragma unroll
    for (int ks = 0; ks < 4; ++ks)
        bcur[ks] = *(const bf16x8*)(gB + ks * 64);

    for (int cc = 0; cc < 16; ++cc) {
        if (cc + 1 < 16) {
            const unsigned char* src = gB + (size_t)(cc + 1) * 16 * IMG_RS;
            #pragma unroll
            for (int ks = 0; ks < 4; ++ks)
                bnxt[ks] = *(const bf16x8*)(src + ks * 64);
        }
        const float en1 = gE[cc * 16];
        const unsigned int code = (unsigned int)(base_w + cc * 16 + nn);

        f32x4 acc[4];
        #pragma unroll
        for (int mt = 0; mt < 4; ++mt) acc[mt] = (f32x4){0.f, 0.f, 0.f, 0.f};
        #pragma unroll
        for (int ks = 0; ks < 4; ++ks)
            #pragma unroll
            for (int mt = 0; mt < 4; ++mt)
                acc[mt] = __builtin_amdgcn_mfma_f32_16x16x32_bf16(a[mt][ks], bcur[ks], acc[mt], 0, 0, 0);

        // packed argmin: s = (||e||^2+1) - 2*dot in (0,2); u32-min == float-min,
        // code in low 10 bits => np tie-break (lowest index)
        #pragma unroll
        for (int mt = 0; mt < 4; ++mt)
            #pragma unroll
            for (int r = 0; r < 4; ++r) {
                float s = fmaf(acc[mt][r], -2.0f, en1);
                unsigned int u = (__float_as_uint(s) & ~1023u) | code;
                best[mt][r] = min(best[mt][r], u);
            }
        #pragma unroll
        for (int ks = 0; ks < 4; ++ks) bcur[ks] = bnxt[ks];
    }

    // in-wave reduce over the 16 code columns (nn)
    #pragma unroll
    for (int mt = 0; mt < 4; ++mt)
        #pragma unroll
        for (int r = 0; r < 4; ++r) {
            unsigned int v = best[mt][r];
            v = min(v, (unsigned int)__shfl_xor((int)v, 1));
            v = min(v, (unsigned int)__shfl_xor((int)v, 2));
            v = min(v, (unsigned int)__shfl_xor((int)v, 4));
            v = min(v, (unsigned int)__shfl_xor((int)v, 8));
            if (nn == 0) wbest[w][mt * 16 + q * 4 + r] = v;   // pos index
        }
    __syncthreads();

    if (t < MB) {
        unsigned int v = min(min(wbest[0][t], wbest[1][t]), min(wbest[2][t], wbest[3][t]));
        unsigned int code = v & 1023u;
        idxs[t] = (unsigned short)code;
        out[IDX_OFF + n0g + t] = (float)code;
    }
    __syncthreads();

    // epilogue: gather chosen rows from bf16 image (L2-hot), z_q store, loss
    {
        int pos = t & 63;
        int c0b = (t >> 6) * 32;
        int myidx = idxs[pos];
        const unsigned char* brow = img + (size_t)myidx * IMG_RS + c0b * 2;
        float* og = out + ZQ_OFF + (size_t)b * C * HW + hw0;
        float ls = 0.f;
        #pragma unroll
        for (int i = 0; i < 4; ++i) {
            ushort4 e0 = *(const ushort4*)(brow + i * 16);       // 8 bf16 = c0..c0+7
            ushort4 e1 = *(const ushort4*)(brow + i * 16 + 8);
            ushort4 z0 = *(ushort4*)&zt[pos * RS + c0b + i * 8];
            ushort4 z1 = *(ushort4*)&zt[pos * RS + c0b + i * 8 + 4];
            unsigned short es[8] = {e0.x, e0.y, e0.z, e0.w, e1.x, e1.y, e1.z, e1.w};
            unsigned short zs[8] = {z0.x, z0.y, z0.z, z0.w, z1.x, z1.y, z1.z, z1.w};
            #pragma unroll
            for (int j = 0; j < 8; ++j) {
                float ev = __uint_as_float((unsigned int)es[j] << 16);
                float zv = __uint_as_float((unsigned int)zs[j] << 16);
                float d = zv - ev;
                ls += d * d;
                og[(size_t)(c0b + i * 8 + j) * HW + pos] = ev;
            }
        }
        #pragma unroll
        for (int off = 32; off; off >>= 1) ls += __shfl_down(ls, off);
        if (lane == 0) lred[w] = ls;
    }
    __syncthreads();

    if (t == 0) {
        atomicAdd(S, lred[0] + lred[1] + lred[2] + lred[3]);
        __threadfence();
        unsigned int old = atomicAdd(cnt, 1u);
        if (old == NBLK - 1) {
            float s = atomicAdd(S, 0.0f);
            out[LOSS_OFF] = 1.25f * s;
            out[COMMIT_OFF] = 0.25f * s;
            out[CODE_OFF] = s;
        }
    }
}

extern "C" void kernel_launch(void* const* d_in, const int* in_sizes, int n_in,
                              void* d_out, int out_size, void* d_ws, size_t ws_size,
                              hipStream_t stream) {
    const float* z = (const float*)d_in[0];
    const float* emb = (const float*)d_in[1];
    float* out = (float*)d_out;
    float* S = (float*)d_ws;
    unsigned int* cnt = (unsigned int*)d_ws + 1;
    float* enorm1 = (float*)((unsigned char*)d_ws + WS_EN_OFF);
    unsigned char* img = (unsigned char*)d_ws + WS_IMG_OFF;

    hipMemsetAsync(d_ws, 0, 64, stream);
    vq_prep<<<K / 8, 256, 0, stream>>>(emb, img, enorm1);
    vq_main<<<NBLK, 256, 0, stream>>>(z, img, enorm1, out, S, cnt);
}

// Round 6
// 144.936 us; speedup vs baseline: 1.1350x; 1.1350x over previous
//
#include <hip/hip_runtime.h>
#include <hip/hip_bf16.h>

#define C 128
#define HW 4096
#define NPOS 65536
#define K 1024
#define MB 64             // positions per block
#define NBLK (NPOS/MB)    // 1024 = exactly 4 blocks/CU
#define RS 136            // row stride in ushorts (272 B, 16B-aligned)
#define IMG_RS 272        // image row stride bytes (matches LDS layout)
#define CHK 64            // codes per chunk
#define NCH (K/CHK)       // 16
#define CHB (CHK*IMG_RS)  // 17408 = 17 KB exact

#define ZQ_OFF 0
#define LOSS_OFF 8388608
#define IDX_OFF 8388609
#define COMMIT_OFF 8454145
#define CODE_OFF 8454146

#define WS_EN_OFF 256     // enorm1[1024] fp32 (||e||^2 + 1)
#define WS_IMG_OFF 8192   // bf16 codebook image, 1024*272 B

typedef __bf16 bf16x8 __attribute__((ext_vector_type(8)));
typedef float f32x4 __attribute__((ext_vector_type(4)));

__global__ void vq_prep(const float* __restrict__ emb, unsigned char* __restrict__ img,
                        float* __restrict__ enorm1) {
    int t = threadIdx.x;
    int r = t >> 5, l = t & 31;          // 8 rows/block, 32 lanes/row
    int k = blockIdx.x * 8 + r;
    float4 v = ((const float4*)emb)[k * 32 + l];
    __hip_bfloat16 h0 = __float2bfloat16(v.x), h1 = __float2bfloat16(v.y),
                   h2 = __float2bfloat16(v.z), h3 = __float2bfloat16(v.w);
    ushort4 pk;
    pk.x = *(unsigned short*)&h0; pk.y = *(unsigned short*)&h1;
    pk.z = *(unsigned short*)&h2; pk.w = *(unsigned short*)&h3;
    *(ushort4*)(img + (size_t)k * IMG_RS + l * 8) = pk;
    float s = v.x * v.x + v.y * v.y + v.z * v.z + v.w * v.w;
    #pragma unroll
    for (int off = 16; off; off >>= 1) s += __shfl_xor(s, off);
    if (l == 0) enorm1[k] = s + 1.0f;
}

__global__ __launch_bounds__(256, 4)
void vq_main(const float* __restrict__ z,
             const unsigned char* __restrict__ img, const float* __restrict__ enorm1,
             float* __restrict__ out, float* __restrict__ S, unsigned int* __restrict__ cnt) {
    __shared__ unsigned short zt[MB * RS];     // 17408 B, z tile bf16
    __shared__ unsigned short bbuf[CHK * RS];  // 17408 B, one codebook chunk
    __shared__ unsigned int wbest[4][MB];      // 1024 B
    __shared__ unsigned short idxs[MB];        // 128 B
    __shared__ float lred[4];

    const int t = threadIdx.x;
    const int w = t >> 6;
    const int lane = t & 63;
    const int nn = lane & 15;
    const int q = lane >> 4;

    const int n0g = blockIdx.x * MB;
    const int b = n0g >> 12;
    const int hw0 = n0g & (HW - 1);
    const float* zg = z + (size_t)b * C * HW + hw0;

    // stage z tile -> LDS bf16 [pos][c], 272 B rows
    {
        int pos = t & 63;
        int c0b = (t >> 6) * 32;
        #pragma unroll
        for (int i = 0; i < 8; ++i) {
            int c0 = c0b + i * 4;
            float f0 = zg[(size_t)(c0 + 0) * HW + pos];
            float f1 = zg[(size_t)(c0 + 1) * HW + pos];
            float f2 = zg[(size_t)(c0 + 2) * HW + pos];
            float f3 = zg[(size_t)(c0 + 3) * HW + pos];
            __hip_bfloat16 h0 = __float2bfloat16(f0), h1 = __float2bfloat16(f1),
                           h2 = __float2bfloat16(f2), h3 = __float2bfloat16(f3);
            ushort4 pk;
            pk.x = *(unsigned short*)&h0; pk.y = *(unsigned short*)&h1;
            pk.z = *(unsigned short*)&h2; pk.w = *(unsigned short*)&h3;
            *(ushort4*)&zt[pos * RS + c0] = pk;
        }
    }
    __syncthreads();

    // A-frags: 4 M-tiles x 4 K-steps (64 VGPRs), reused for all 1024 codes
    bf16x8 a[4][4];
    #pragma unroll
    for (int mt = 0; mt < 4; ++mt)
        #pragma unroll
        for (int ks = 0; ks < 4; ++ks)
            a[mt][ks] = *(bf16x8*)&zt[(mt * 16 + nn) * RS + ks * 32 + q * 8];

    unsigned int best[4][4];
    #pragma unroll
    for (int mt = 0; mt < 4; ++mt)
        #pragma unroll
        for (int r = 0; r < 4; ++r) best[mt][r] = 0xFFFFFFFFu;

    for (int ch = 0; ch < NCH; ++ch) {
        // issue contiguous 17 KB chunk -> LDS (17 x 1KB wave-instrs, split over waves)
        const unsigned char* src = img + (size_t)ch * CHB;
        for (int j = w; j < 17; j += 4) {
            __builtin_amdgcn_global_load_lds(
                (const __attribute__((address_space(1))) unsigned int*)(src + j * 1024 + lane * 16),
                (__attribute__((address_space(3))) unsigned int*)((unsigned char*)bbuf + j * 1024),
                16, 0, 0);
        }
        __syncthreads();   // drain + barrier: bbuf ready for all waves

        const int row = w * 16 + nn;               // wave w owns 16 codes of the chunk
        bf16x8 bf[4];
        #pragma unroll
        for (int ks = 0; ks < 4; ++ks)
            bf[ks] = *(bf16x8*)&bbuf[row * RS + ks * 32 + q * 8];
        const float en1 = enorm1[ch * CHK + row];  // L2-hot
        const unsigned int code = (unsigned int)(ch * CHK + row);

        f32x4 acc[4];
        #pragma unroll
        for (int mt = 0; mt < 4; ++mt) acc[mt] = (f32x4){0.f, 0.f, 0.f, 0.f};
        #pragma unroll
        for (int ks = 0; ks < 4; ++ks)
            #pragma unroll
            for (int mt = 0; mt < 4; ++mt)
                acc[mt] = __builtin_amdgcn_mfma_f32_16x16x32_bf16(a[mt][ks], bf[ks], acc[mt], 0, 0, 0);

        // packed argmin: s = (||e||^2+1) - 2*dot in (0,2); u32-min == float-min,
        // code in low 10 bits => np tie-break (lowest index)
        #pragma unroll
        for (int mt = 0; mt < 4; ++mt)
            #pragma unroll
            for (int r = 0; r < 4; ++r) {
                float s = fmaf(acc[mt][r], -2.0f, en1);
                unsigned int u = (__float_as_uint(s) & ~1023u) | code;
                best[mt][r] = min(best[mt][r], u);
            }
        __syncthreads();   // all waves done with bbuf before next chunk overwrites
    }

    // in-wave reduce over 16 code columns (nn = lane bits 0..3)
    #pragma unroll
    for (int mt = 0; mt < 4; ++mt)
        #pragma unroll
        for (int r = 0; r < 4; ++r) {
            unsigned int v = best[mt][r];
            v = min(v, (unsigned int)__shfl_xor((int)v, 1));
            v = min(v, (unsigned int)__shfl_xor((int)v, 2));
            v = min(v, (unsigned int)__shfl_xor((int)v, 4));
            v = min(v, (unsigned int)__shfl_xor((int)v, 8));
            if (nn == 0) wbest[w][mt * 16 + q * 4 + r] = v;   // pos = mt*16+q*4+r
        }
    __syncthreads();

    if (t < MB) {
        unsigned int v = min(min(wbest[0][t], wbest[1][t]), min(wbest[2][t], wbest[3][t]));
        unsigned int code = v & 1023u;
        idxs[t] = (unsigned short)code;
        out[IDX_OFF + n0g + t] = (float)code;
    }
    __syncthreads();

    // epilogue: gather chosen rows from bf16 image (L2-hot), z_q store, loss
    {
        int pos = t & 63;
        int c0b = (t >> 6) * 32;
        int myidx = idxs[pos];
        const unsigned char* brow = img + (size_t)myidx * IMG_RS + c0b * 2;
        float* og = out + ZQ_OFF + (size_t)b * C * HW + hw0;
        float ls = 0.f;
        #pragma unroll
        for (int i = 0; i < 4; ++i) {
            ushort4 e0 = *(const ushort4*)(brow + i * 16);
            ushort4 e1 = *(const ushort4*)(brow + i * 16 + 8);
            ushort4 z0 = *(ushort4*)&zt[pos * RS + c0b + i * 8];
            ushort4 z1 = *(ushort4*)&zt[pos * RS + c0b + i * 8 + 4];
            unsigned short es[8] = {e0.x, e0.y, e0.z, e0.w, e1.x, e1.y, e1.z, e1.w};
            unsigned short zs[8] = {z0.x, z0.y, z0.z, z0.w, z1.x, z1.y, z1.z, z1.w};
            #pragma unroll
            for (int j = 0; j < 8; ++j) {
                float ev = __uint_as_float((unsigned int)es[j] << 16);
                float zv = __uint_as_float((unsigned int)zs[j] << 16);
                float d = zv - ev;
                ls += d * d;
                og[(size_t)(c0b + i * 8 + j) * HW + pos] = ev;
            }
        }
        #pragma unroll
        for (int off = 32; off; off >>= 1) ls += __shfl_down(ls, off);
        if (lane == 0) lred[w] = ls;
    }
    __syncthreads();

    if (t == 0) {
        atomicAdd(S, lred[0] + lred[1] + lred[2] + lred[3]);
        __threadfence();
        unsigned int old = atomicAdd(cnt, 1u);
        if (old == NBLK - 1) {
            float s = atomicAdd(S, 0.0f);
            out[LOSS_OFF] = 1.25f * s;
            out[COMMIT_OFF] = 0.25f * s;
            out[CODE_OFF] = s;
        }
    }
}

extern "C" void kernel_launch(void* const* d_in, const int* in_sizes, int n_in,
                              void* d_out, int out_size, void* d_ws, size_t ws_size,
                              hipStream_t stream) {
    const float* z = (const float*)d_in[0];
    const float* emb = (const float*)d_in[1];
    float* out = (float*)d_out;
    float* S = (float*)d_ws;
    unsigned int* cnt = (unsigned int*)d_ws + 1;
    float* enorm1 = (float*)((unsigned char*)d_ws + WS_EN_OFF);
    unsigned char* img = (unsigned char*)d_ws + WS_IMG_OFF;

    hipMemsetAsync(d_ws, 0, 64, stream);
    vq_prep<<<K / 8, 256, 0, stream>>>(emb, img, enorm1);
    vq_main<<<NBLK, 256, 0, stream>>>(z, img, enorm1, out, S, cnt);
}